// Round 11
// baseline (520.439 us; speedup 1.0000x reference)
//
#include <hip/hip_runtime.h>

#define N_TOK 131072
#define KC    1024
#define DIM   256
#define GAP_THR 5e-4f
#define NBLK  (N_TOK / 128)      // 1024 token blocks

typedef __attribute__((ext_vector_type(8)))  short bf16x8;
typedef __attribute__((ext_vector_type(16))) float f32x16;

__device__ __forceinline__ unsigned short f2bf(float f) {
    unsigned int u = __float_as_uint(f);
    unsigned int r = (u + 0x7fffu + ((u >> 16) & 1u)) >> 16;   // RNE
    return (unsigned short)r;
}

// ================= ws layout =================
// 0       : cb16F (bf16)     524288 B   fragment-ordered: [g(32)][step(16)][lane(64)][16B]
// 524288  : cnsF  (f32)        4096 B   [g(32)][hi(2)][r(16)] = -cnorm/2
// 528384  : cnorm (f32)        4096 B
// 532480  : cbT   (f32)     1048576 B   cbT[d4][code][4] transposed codebook (recheck)
// 1581056 : fcount (u32)         64 B
// 1581120 : flist (int)     4194304 B   entry = row | (blk << 17), one per pair
// 5775424 : rck   (u64)     1048576 B   per-row (dq_bits<<32 | code) atomicMin
// 6824000 : lparts (f64)       8192 B
#define WS_NEED 6832192ull

// cb -> fragment-ordered bf16 + cnsF + f64 norms (one wave per code); zeroes fcount
__global__ void vq_prep_cb(const float* __restrict__ cb, unsigned short* __restrict__ cb16F,
                           float* __restrict__ cnsF, float* __restrict__ cnorm,
                           unsigned int* __restrict__ fcount) {
    if (blockIdx.x == 0 && threadIdx.x == 0) *fcount = 0u;
    int code = blockIdx.x * 4 + (threadIdx.x >> 6);
    int lane = threadIdx.x & 63;
    float4 v = ((const float4*)cb)[(size_t)code * 64 + lane];
    ushort4 h;
    h.x = f2bf(v.x); h.y = f2bf(v.y); h.z = f2bf(v.z); h.w = f2bf(v.w);
    // fragment destination for dims d = 4*lane .. +4 (stays within one 8-dim half)
    int d = lane * 4;
    int kb = d >> 6, ks = (d >> 4) & 3, hi = (d >> 3) & 1;
    int step = kb * 4 + ks;
    int g = code >> 5, l31 = code & 31;
    size_t sidx = ((size_t)(g * 16 + step) * 64 + hi * 32 + l31) * 8 + (d & 7);
    *(ushort4*)(cb16F + sidx) = h;           // 8 B aligned
    double s = 0.0;
    s = fma((double)v.x, (double)v.x, s);
    s = fma((double)v.y, (double)v.y, s);
    s = fma((double)v.z, (double)v.z, s);
    s = fma((double)v.w, (double)v.w, s);
    #pragma unroll
    for (int off = 32; off > 0; off >>= 1) s += __shfl_xor(s, off);
    if (lane == 0) {
        float cn = (float)s;
        cnorm[code] = cn;
        int row = code & 31;                 // C-layout row of this code within its group
        int hic = (row >> 2) & 1;
        int rc  = (row & 3) | ((row >> 3) << 2);
        cnsF[(g * 2 + hic) * 16 + rc] = -0.5f * cn;   // exact: acc-init = -cc/2
    }
}

// cbT[d4][code][4] = cb[code][4*d4 .. 4*d4+4)   (for the exact recheck)
__global__ void vq_transpose(const float* __restrict__ cb, float* __restrict__ cbT) {
    int g = blockIdx.x * 256 + threadIdx.x;       // [0, 65536)
    int d4 = g >> 10, code = g & 1023;
    ((float4*)cbT)[g] = ((const float4*)cb)[(size_t)code * 64 + d4];
}

// ---- Fused scores: NO LDS / NO barriers in the main loop.
// Block: 4 waves; wave = 32 tokens x (64 codes per sub-block) x 16 sub-blocks.
// B (tokens) register-resident bf16 frags; A (codes) coalesced 1KB wave-loads from
// L2-resident fragment-ordered cb16F; cnorm enters via f32-exact acc init (-cc/2).
// 4 waves/SIMD target: acc[2]=32 + bfr=64 VGPR, launch_bounds(256,4).
__global__ __launch_bounds__(256, 4)
void vq_scores_fused(const float* __restrict__ z, const unsigned short* __restrict__ cb16F,
                     const float* __restrict__ cnsF, const float* __restrict__ cb,
                     float* __restrict__ out, float* __restrict__ out_idx,
                     int* __restrict__ flist, unsigned int* __restrict__ fcount,
                     unsigned long long* __restrict__ rck, double* __restrict__ lparts)
{
    __shared__ float  bm1L[16][128];    // 8 KB : per-sub-block per-token min
    __shared__ double sredD[4];

    const int tid  = threadIdx.x;
    const int lane = tid & 63;
    const int l31  = lane & 31;
    const int hi   = lane >> 5;
    const int wid  = tid >> 6;
    const int tb   = blockIdx.x;
    const int ltok = wid * 32 + l31;    // local token 0..127

    // ---- B fragments from global f32 (hi-pairs consume 64B line chunks) + f64 zz ----
    bf16x8 bfr[4][4];
    const float* zr = z + (size_t)(tb * 128 + ltok) * DIM;
    double s = 0.0;
    #pragma unroll
    for (int kb = 0; kb < 4; ++kb)
        #pragma unroll
        for (int ks = 0; ks < 4; ++ks) {
            const int d0 = kb * 64 + ks * 16 + hi * 8;
            float4 x = *(const float4*)(zr + d0);
            float4 y = *(const float4*)(zr + d0 + 4);
            s = fma((double)x.x, (double)x.x, s);
            s = fma((double)x.y, (double)x.y, s);
            s = fma((double)x.z, (double)x.z, s);
            s = fma((double)x.w, (double)x.w, s);
            s = fma((double)y.x, (double)y.x, s);
            s = fma((double)y.y, (double)y.y, s);
            s = fma((double)y.z, (double)y.z, s);
            s = fma((double)y.w, (double)y.w, s);
            bf16x8 v;
            v[0] = (short)f2bf(x.x); v[1] = (short)f2bf(x.y);
            v[2] = (short)f2bf(x.z); v[3] = (short)f2bf(x.w);
            v[4] = (short)f2bf(y.x); v[5] = (short)f2bf(y.y);
            v[6] = (short)f2bf(y.z); v[7] = (short)f2bf(y.w);
            bfr[kb][ks] = v;
        }
    s += __shfl_xor(s, 32);             // partner lane holds the other dim-half
    const float zzr = (float)s;         // uniform per-row shift: argmin-invariant

    float gm1 = 3.0e38f, gm2 = 3.0e38f; int gid_ = 0x7fffffff;
    const bf16x8* AF = (const bf16x8*)cb16F;     // 16B fragment units

    #pragma unroll 1
    for (int sb = 0; sb < 16; ++sb) {
        // acc init = -cc/2 (f32 exact), broadcast loads from cnsF
        f32x16 acc[2];
        #pragma unroll
        for (int gi = 0; gi < 2; ++gi) {
            const float4* cp = (const float4*)(cnsF + (((sb * 2 + gi) * 2 + hi) << 4));
            float4 c0 = cp[0], c1 = cp[1], c2 = cp[2], c3 = cp[3];
            acc[gi][0]  = c0.x; acc[gi][1]  = c0.y; acc[gi][2]  = c0.z; acc[gi][3]  = c0.w;
            acc[gi][4]  = c1.x; acc[gi][5]  = c1.y; acc[gi][6]  = c1.z; acc[gi][7]  = c1.w;
            acc[gi][8]  = c2.x; acc[gi][9]  = c2.y; acc[gi][10] = c2.z; acc[gi][11] = c2.w;
            acc[gi][12] = c3.x; acc[gi][13] = c3.y; acc[gi][14] = c3.z; acc[gi][15] = c3.w;
        }

        #pragma unroll
        for (int kb = 0; kb < 4; ++kb)
            #pragma unroll
            for (int ks = 0; ks < 4; ++ks) {
                const bf16x8 bv = bfr[kb][ks];
                #pragma unroll
                for (int gi = 0; gi < 2; ++gi) {
                    bf16x8 af = AF[(size_t)((sb * 2 + gi) * 16 + kb * 4 + ks) * 64 + lane];
                    acc[gi] = __builtin_amdgcn_mfma_f32_32x32x16_bf16(af, bv, acc[gi], 0, 0, 0);
                }
            }

        // epilogue (register-only): dq = fmaf(acc, -2, zz); top-2 + lowest-index.
        // C layout (32x32): col=lane&31 (token), row=(r&3)+8*(r>>2)+4*hi (code)
        float c1v = 3.0e38f, c2v = 3.0e38f;
        #pragma unroll
        for (int gi = 0; gi < 2; ++gi)
            #pragma unroll
            for (int r = 0; r < 16; ++r) {
                float dq = fmaf(acc[gi][r], -2.0f, zzr);
                acc[gi][r] = dq;
                float hv = fmaxf(c1v, dq);
                c1v = fminf(c1v, dq);
                c2v = fminf(c2v, hv);              // dup minima -> gap 0 -> flagged
            }
        int ci = 0x7fffffff;
        #pragma unroll
        for (int gi = 0; gi < 2; ++gi)
            #pragma unroll
            for (int r = 0; r < 16; ++r) {
                int code = (sb * 2 + gi) * 32 + (r & 3) + 8 * (r >> 2) + 4 * hi;
                ci = min(ci, (acc[gi][r] == c1v) ? code : 0x7fffffff);
            }
        // merge lane <-> lane^32 (same token, other code rows)
        float o1 = __shfl_xor(c1v, 32);
        float o2 = __shfl_xor(c2v, 32);
        int  oi  = __shfl_xor(ci, 32);
        float nm2 = fminf(fminf(c2v, o2), fmaxf(c1v, o1));
        int  ni  = (o1 < c1v || (o1 == c1v && oi < ci)) ? oi : ci;
        float nm1 = fminf(c1v, o1);
        if (hi == 0) bm1L[sb][ltok] = nm1;
        float ng2 = fminf(fminf(gm2, nm2), fmaxf(gm1, nm1));
        if (nm1 < gm1 || (nm1 == gm1 && ni < gid_)) { gm1 = nm1; gid_ = ni; }
        gm2 = ng2;
    }

    // ---- flag pairs + provisional index (hi==0 lane reads back its own bm1L writes) ----
    const int rowg = tb * 128 + ltok;
    if (hi == 0) {
        out_idx[rowg] = (float)gid_;
        float gap = gm2 - gm1;
        if (!(gap > GAP_THR)) {           // near-tie or NaN safety -> exact recheck
            rck[rowg] = ~0ull;
            #pragma unroll
            for (int c = 0; c < 8; ++c) {
                float bmin = fminf(bm1L[2 * c][ltok], bm1L[2 * c + 1][ltok]);
                if (bmin <= gm1 + GAP_THR) {
                    unsigned int p = atomicAdd(fcount, 1u);
                    flist[p] = rowg | (c << 17);
                }
            }
        }
    }

    // ---- fused z_st + loss: wave writes its own 32 rows (z re-read L2/L3-hot) ----
    double ls = 0.0;
    #pragma unroll 4
    for (int r = 0; r < 32; ++r) {
        int idx = __shfl(gid_, r);                       // wave-uniform per row
        size_t row = (size_t)tb * 128 + wid * 32 + r;
        float4 zv = ((const float4*)z)[row * 64 + lane];
        float4 cv = ((const float4*)cb)[(size_t)idx * 64 + lane];
        float4 o;
        o.x = zv.x + (cv.x - zv.x);
        o.y = zv.y + (cv.y - zv.y);
        o.z = zv.z + (cv.z - zv.z);
        o.w = zv.w + (cv.w - zv.w);
        ((float4*)out)[row * 64 + lane] = o;
        float dx = zv.x - cv.x, dy = zv.y - cv.y, dz = zv.z - cv.z, dw = zv.w - cv.w;
        ls += (double)dx * dx + (double)dy * dy + (double)dz * dz + (double)dw * dw;
    }
    #pragma unroll
    for (int off = 32; off > 0; off >>= 1) ls += __shfl_down(ls, off);
    if (lane == 0) sredD[wid] = ls;
    __syncthreads();
    if (tid == 0) lparts[tb] = (sredD[0] + sredD[1]) + (sredD[2] + sredD[3]);
}

// ---- exact np-f32-chain recheck: ONE WAVE PER (row, block) PAIR, no barriers. ----
__global__ __launch_bounds__(256)
void vq_recheck_pairs(const float* __restrict__ z, const float* __restrict__ cbT,
                      const float* __restrict__ cnorm, const int* __restrict__ flist,
                      const unsigned int* __restrict__ fcount,
                      unsigned long long* __restrict__ rck)
{
    const int tid  = threadIdx.x;
    const int wid  = tid >> 6;
    const int lane = tid & 63;
    const unsigned int cnt = *fcount;

    for (unsigned int p = blockIdx.x * 4 + wid; p < cnt; p += gridDim.x * 4) {
        const int e   = flist[p];
        const int row = e & 0x1FFFF;
        const int blk = ((unsigned int)e) >> 17;
        const float* zr = z + (size_t)row * DIM;

        float4 zv = ((const float4*)zr)[lane];
        double s = 0.0;
        s = fma((double)zv.x, (double)zv.x, s);
        s = fma((double)zv.y, (double)zv.y, s);
        s = fma((double)zv.z, (double)zv.z, s);
        s = fma((double)zv.w, (double)zv.w, s);
        #pragma unroll
        for (int off = 32; off > 0; off >>= 1) s += __shfl_xor(s, off);
        const float zz = (float)s;

        const int c0 = blk * 128 + lane;        // lane's two codes (c0 < c0+64)
        float e0 = 0.0f, e1 = 0.0f;
        #pragma unroll 8
        for (int d4 = 0; d4 < 64; ++d4) {       // strict sequential k = 0..255
            float4 zq = ((const float4*)zr)[d4];             // wave-uniform, L1-hot
            float4 a  = ((const float4*)cbT)[d4 * KC + c0];  // coalesced over lanes
            float4 b  = ((const float4*)cbT)[d4 * KC + c0 + 64];
            e0 = fmaf(zq.x, a.x, e0); e0 = fmaf(zq.y, a.y, e0);
            e0 = fmaf(zq.z, a.z, e0); e0 = fmaf(zq.w, a.w, e0);
            e1 = fmaf(zq.x, b.x, e1); e1 = fmaf(zq.y, b.y, e1);
            e1 = fmaf(zq.z, b.z, e1); e1 = fmaf(zq.w, b.w, e1);
        }
        const float dq0 = fmaf(e0, -2.0f, zz + cnorm[c0]);       // fl(fl(zz+cc) - fl(2e))
        const float dq1 = fmaf(e1, -2.0f, zz + cnorm[c0 + 64]);
        unsigned long long k0 = ((unsigned long long)__float_as_uint(dq0) << 32) | (unsigned int)c0;
        unsigned long long k1 = ((unsigned long long)__float_as_uint(dq1) << 32) | (unsigned int)(c0 + 64);
        unsigned long long k = k0 < k1 ? k0 : k1;
        #pragma unroll
        for (int off = 32; off > 0; off >>= 1) {
            unsigned long long o = __shfl_xor(k, off);
            k = o < k ? o : k;
        }
        if (lane == 0) atomicMin(&rck[row], k);
    }
}

// ---- fixup: one wave per pair (duplicates idempotent): final idx + z_st row rewrite
__global__ __launch_bounds__(256)
void vq_fixup(const float* __restrict__ z, const float* __restrict__ cb,
              const int* __restrict__ flist, const unsigned int* __restrict__ fcount,
              const unsigned long long* __restrict__ rck,
              float* __restrict__ out, float* __restrict__ out_idx)
{
    const int tid  = threadIdx.x;
    const int wid  = tid >> 6;
    const int lane = tid & 63;
    const unsigned int cnt = *fcount;

    for (unsigned int p = blockIdx.x * 4 + wid; p < cnt; p += gridDim.x * 4) {
        const int row  = flist[p] & 0x1FFFF;
        const int code = (int)(unsigned int)rck[row];   // low 32 bits = winning code
        float4 zv = ((const float4*)z)[(size_t)row * 64 + lane];
        float4 cv = ((const float4*)cb)[(size_t)code * 64 + lane];
        float4 o;
        o.x = zv.x + (cv.x - zv.x);
        o.y = zv.y + (cv.y - zv.y);
        o.z = zv.z + (cv.z - zv.z);
        o.w = zv.w + (cv.w - zv.w);
        ((float4*)out)[(size_t)row * 64 + lane] = o;
        if (lane == 0) out_idx[row] = (float)code;
    }
}

__global__ void vq_loss_final(const double* __restrict__ lparts, float* __restrict__ out_loss) {
    __shared__ double s[256];
    const int tid = threadIdx.x;
    double a = 0.0;
    for (int i = tid; i < NBLK; i += 256) a += lparts[i];
    s[tid] = a;
    __syncthreads();
    for (int sft = 128; sft > 0; sft >>= 1) {
        if (tid < sft) s[tid] += s[tid + sft];
        __syncthreads();
    }
    if (tid == 0) {
        float mean = (float)(s[0] / (double)((size_t)N_TOK * DIM));
        out_loss[0] = 0.25f * mean + mean;   // commit + codebook, reference op order
    }
}

extern "C" void kernel_launch(void* const* d_in, const int* in_sizes, int n_in,
                              void* d_out, int out_size, void* d_ws, size_t ws_size,
                              hipStream_t stream) {
    const float* z  = (const float*)d_in[0];
    const float* cb = (const float*)d_in[1];
    float* out = (float*)d_out;
    char* ws = (char*)d_ws;

    unsigned short*     cb16F  = (unsigned short*)(ws);
    float*              cnsF   = (float*)(ws + 524288);
    float*              cnorm  = (float*)(ws + 528384);
    float*              cbT    = (float*)(ws + 532480);
    unsigned int*       fcount = (unsigned int*)(ws + 1581056);
    int*                flist  = (int*)(ws + 1581120);
    unsigned long long* rck    = (unsigned long long*)(ws + 5775424);
    double*             lparts = (double*)(ws + 6824000);

    float* out_idx  = out + (size_t)N_TOK * DIM;
    float* out_loss = out_idx + N_TOK;

    vq_prep_cb<<<KC / 4, 256, 0, stream>>>(cb, cb16F, cnsF, cnorm, fcount);
    vq_transpose<<<(KC * DIM / 4) / 256, 256, 0, stream>>>(cb, cbT);
    vq_scores_fused<<<NBLK, 256, 0, stream>>>(z, cb16F, cnsF, cb, out, out_idx,
                                              flist, fcount, rck, lparts);
    vq_recheck_pairs<<<1024, 256, 0, stream>>>(z, cbT, cnorm, flist, fcount, rck);
    vq_fixup<<<512, 256, 0, stream>>>(z, cb, flist, fcount, rck, out, out_idx);
    vq_loss_final<<<1, 256, 0, stream>>>(lparts, out_loss);
}

// Round 12
// 432.315 us; speedup vs baseline: 1.2038x; 1.2038x over previous
//
#include <hip/hip_runtime.h>

#define N_TOK 131072
#define KC    1024
#define DIM   256
#define GAP_THR 5e-4f
#define NBLK  (N_TOK / 128)      // 1024 token blocks

typedef __attribute__((ext_vector_type(8)))  short bf16x8;
typedef __attribute__((ext_vector_type(16))) float f32x16;

__device__ __forceinline__ unsigned short f2bf(float f) {
    unsigned int u = __float_as_uint(f);
    unsigned int r = (u + 0x7fffu + ((u >> 16) & 1u)) >> 16;   // RNE
    return (unsigned short)r;
}

// ================= ws layout =================
// 0       : cb16F (bf16)     524288 B   fragment-ordered LDS image: unit (tile,step,hi,l31)
// 524288  : cnsF  (f32)        4096 B   [tile(32)][hi(2)][r(16)] = -cnorm/2
// 528384  : cnorm (f32)        4096 B
// 532480  : cbT   (f32)     1048576 B   cbT[d4][code][4] transposed codebook (recheck)
// 1581056 : fcount (u32)         64 B
// 1581120 : flist (int)     4194304 B   entry = row | (blk << 17), one per pair
// 5775424 : rck   (u64)     1048576 B   per-row (dq_bits<<32 | code) atomicMin
// 6824000 : lparts (f64)       8192 B
#define WS_NEED 6832192ull

// cb -> fragment-ordered bf16 + cnsF + f64 norms (one wave per code); zeroes fcount
__global__ void vq_prep_cb(const float* __restrict__ cb, unsigned short* __restrict__ cb16F,
                           float* __restrict__ cnsF, float* __restrict__ cnorm,
                           unsigned int* __restrict__ fcount) {
    if (blockIdx.x == 0 && threadIdx.x == 0) *fcount = 0u;
    int code = blockIdx.x * 4 + (threadIdx.x >> 6);
    int lane = threadIdx.x & 63;
    float4 v = ((const float4*)cb)[(size_t)code * 64 + lane];
    ushort4 h;
    h.x = f2bf(v.x); h.y = f2bf(v.y); h.z = f2bf(v.z); h.w = f2bf(v.w);
    // fragment destination for dims d = 4*lane .. +4 (stays within one 8-dim unit)
    int d = lane * 4;
    int kb = d >> 6, ks = (d >> 4) & 3, hi = (d >> 3) & 1;
    int step = kb * 4 + ks;
    int g = code >> 5, l31 = code & 31;
    size_t sidx = ((size_t)(g * 16 + step) * 64 + hi * 32 + l31) * 8 + (d & 7);
    *(ushort4*)(cb16F + sidx) = h;           // 8 B aligned
    double s = 0.0;
    s = fma((double)v.x, (double)v.x, s);
    s = fma((double)v.y, (double)v.y, s);
    s = fma((double)v.z, (double)v.z, s);
    s = fma((double)v.w, (double)v.w, s);
    #pragma unroll
    for (int off = 32; off > 0; off >>= 1) s += __shfl_xor(s, off);
    if (lane == 0) {
        float cn = (float)s;
        cnorm[code] = cn;
        int row = code & 31;                 // C-layout row within the 32-code tile
        int hic = (row >> 2) & 1;
        int rc  = (row & 3) | ((row >> 3) << 2);
        cnsF[(g * 2 + hic) * 16 + rc] = -0.5f * cn;   // exact: acc-init = -cc/2
    }
}

// cbT[d4][code][4] = cb[code][4*d4 .. 4*d4+4)   (for the exact recheck)
__global__ void vq_transpose(const float* __restrict__ cb, float* __restrict__ cbT) {
    int g = blockIdx.x * 256 + threadIdx.x;       // [0, 65536)
    int d4 = g >> 10, code = g & 1023;
    ((float4*)cbT)[g] = ((const float4*)cb)[(size_t)code * 64 + d4];
}

// ---- Fused scores: double-buffered global_load_lds prefetch pipeline.
// Block: 4 waves x 32 tokens. 32 tiles of 32 codes; per tile: stage-next (DMA),
// 16 contiguous ds_read_b128 (conflict-free) + 16 MFMA + register epilogue, 1 barrier.
// cnorm enters via f32-exact acc init (-cc/2). LDS 36.5 KB -> 4 blocks/CU.
__global__ __launch_bounds__(256, 3)
void vq_scores_fused(const float* __restrict__ z, const unsigned short* __restrict__ cb16F,
                     const float* __restrict__ cnsF, const float* __restrict__ cb,
                     float* __restrict__ out, float* __restrict__ out_idx,
                     int* __restrict__ flist, unsigned int* __restrict__ fcount,
                     unsigned long long* __restrict__ rck, double* __restrict__ lparts)
{
    __shared__ uint4  cA[2][1024];      // 2 x 16 KB double-buffered code tile (LDS image)
    __shared__ float  bm1L[8][128];     // 4 KB : per-cbk(128 codes) per-token min
    __shared__ double sredD[4];

    const int tid  = threadIdx.x;
    const int lane = tid & 63;
    const int l31  = lane & 31;
    const int hi   = lane >> 5;
    const int wid  = tid >> 6;
    const int tb   = blockIdx.x;
    const int ltok = wid * 32 + l31;    // local token 0..127

    // ---- B fragments from global f32 (hi-pairs consume 64B line chunks) + f64 zz ----
    bf16x8 bfr[4][4];
    const float* zr = z + (size_t)(tb * 128 + ltok) * DIM;
    double s = 0.0;
    #pragma unroll
    for (int kb = 0; kb < 4; ++kb)
        #pragma unroll
        for (int ks = 0; ks < 4; ++ks) {
            const int d0 = kb * 64 + ks * 16 + hi * 8;
            float4 x = *(const float4*)(zr + d0);
            float4 y = *(const float4*)(zr + d0 + 4);
            s = fma((double)x.x, (double)x.x, s);
            s = fma((double)x.y, (double)x.y, s);
            s = fma((double)x.z, (double)x.z, s);
            s = fma((double)x.w, (double)x.w, s);
            s = fma((double)y.x, (double)y.x, s);
            s = fma((double)y.y, (double)y.y, s);
            s = fma((double)y.z, (double)y.z, s);
            s = fma((double)y.w, (double)y.w, s);
            bf16x8 v;
            v[0] = (short)f2bf(x.x); v[1] = (short)f2bf(x.y);
            v[2] = (short)f2bf(x.z); v[3] = (short)f2bf(x.w);
            v[4] = (short)f2bf(y.x); v[5] = (short)f2bf(y.y);
            v[6] = (short)f2bf(y.z); v[7] = (short)f2bf(y.w);
            bfr[kb][ks] = v;
        }
    s += __shfl_xor(s, 32);             // partner lane holds the other dim-half
    const float zzr = (float)s;         // uniform per-row shift: argmin-invariant

    // DMA stage of one 16 KB tile: 4 waves x 4 calls x 64 lanes x 16 B (linear copy)
    #define STAGE(BUF, TILE) do {                                                        \
        const char* gs_ = (const char*)cb16F + ((size_t)(TILE) << 14)                    \
                          + ((size_t)(wid * 4) << 10) + (size_t)lane * 16;               \
        char* ls_ = (char*)&cA[BUF][0] + ((size_t)(wid * 4) << 10);                      \
        _Pragma("unroll")                                                                \
        for (int i_ = 0; i_ < 4; ++i_)                                                   \
            __builtin_amdgcn_global_load_lds(                                            \
                (const __attribute__((address_space(1))) void*)(gs_ + i_ * 1024),        \
                (__attribute__((address_space(3))) void*)(ls_ + i_ * 1024), 16, 0, 0);   \
    } while (0)

    float gm1 = 3.0e38f, gm2 = 3.0e38f; int gid_ = 0x7fffffff;
    float bmrun = 3.0e38f;
    int cur = 0;

    STAGE(0, 0);
    __syncthreads();

    #pragma unroll 1
    for (int t = 0; t < 32; ++t) {
        if (t + 1 < 32) STAGE(cur ^ 1, t + 1);       // prefetch next tile (hidden)

        // acc init = -cc/2 (f32 exact), broadcast loads from cnsF
        f32x16 acc;
        {
            const float4* cp = (const float4*)(cnsF + (((t * 2 + hi)) << 4));
            float4 c0 = cp[0], c1 = cp[1], c2 = cp[2], c3 = cp[3];
            acc[0]  = c0.x; acc[1]  = c0.y; acc[2]  = c0.z; acc[3]  = c0.w;
            acc[4]  = c1.x; acc[5]  = c1.y; acc[6]  = c1.z; acc[7]  = c1.w;
            acc[8]  = c2.x; acc[9]  = c2.y; acc[10] = c2.z; acc[11] = c2.w;
            acc[12] = c3.x; acc[13] = c3.y; acc[14] = c3.z; acc[15] = c3.w;
        }

        const bf16x8* AF = (const bf16x8*)&cA[cur][0];
        #pragma unroll
        for (int step = 0; step < 16; ++step) {      // k ascending (kb*4+ks)
            bf16x8 af = AF[step * 64 + lane];        // contiguous 1KB wave read
            acc = __builtin_amdgcn_mfma_f32_32x32x16_bf16(af, bfr[step >> 2][step & 3], acc, 0, 0, 0);
        }

        // epilogue (register-only): dq = fmaf(acc, -2, zz); top-2 + lowest-index.
        // C layout (32x32): col=lane&31 (token), row=(r&3)+8*(r>>2)+4*hi (code)
        float c1v = 3.0e38f, c2v = 3.0e38f;
        #pragma unroll
        for (int r = 0; r < 16; ++r) {
            float dq = fmaf(acc[r], -2.0f, zzr);
            acc[r] = dq;
            float hv = fmaxf(c1v, dq);
            c1v = fminf(c1v, dq);
            c2v = fminf(c2v, hv);                    // dup minima -> gap 0 -> flagged
        }
        int ci = 0x7fffffff;
        #pragma unroll
        for (int r = 0; r < 16; ++r) {
            int code = t * 32 + (r & 3) + 8 * (r >> 2) + 4 * hi;
            ci = min(ci, (acc[r] == c1v) ? code : 0x7fffffff);
        }
        // merge lane <-> lane^32 (same token, other code rows)
        float o1 = __shfl_xor(c1v, 32);
        float o2 = __shfl_xor(c2v, 32);
        int  oi  = __shfl_xor(ci, 32);
        float nm2 = fminf(fminf(c2v, o2), fmaxf(c1v, o1));
        int  ni  = (o1 < c1v || (o1 == c1v && oi < ci)) ? oi : ci;
        float nm1 = fminf(c1v, o1);
        // per-cbk(4 tiles) block-min accumulation
        bmrun = fminf(bmrun, nm1);
        if ((t & 3) == 3) {
            if (hi == 0) bm1L[t >> 2][ltok] = bmrun;
            bmrun = 3.0e38f;
        }
        // running top-2 (registers)
        float ng2 = fminf(fminf(gm2, nm2), fmaxf(gm1, nm1));
        if (nm1 < gm1 || (nm1 == gm1 && ni < gid_)) { gm1 = nm1; gid_ = ni; }
        gm2 = ng2;

        __syncthreads();                 // drains prefetch (vmcnt) + ds_reads; swap
        cur ^= 1;
    }
    #undef STAGE

    // ---- flag pairs + provisional index (hi==0 lane reads back its own bm1L writes) ----
    const int rowg = tb * 128 + ltok;
    if (hi == 0) {
        out_idx[rowg] = (float)gid_;
        float gap = gm2 - gm1;
        if (!(gap > GAP_THR)) {           // near-tie or NaN safety -> exact recheck
            rck[rowg] = ~0ull;
            #pragma unroll
            for (int c = 0; c < 8; ++c)
                if (bm1L[c][ltok] <= gm1 + GAP_THR) {
                    unsigned int p = atomicAdd(fcount, 1u);
                    flist[p] = rowg | (c << 17);
                }
        }
    }

    // ---- fused z_st + loss: wave writes its own 32 rows (z re-read L2/L3-hot) ----
    double ls = 0.0;
    #pragma unroll 4
    for (int r = 0; r < 32; ++r) {
        int idx = __shfl(gid_, r);                       // wave-uniform per row
        size_t row = (size_t)tb * 128 + wid * 32 + r;
        float4 zv = ((const float4*)z)[row * 64 + lane];
        float4 cv = ((const float4*)cb)[(size_t)idx * 64 + lane];
        float4 o;
        o.x = zv.x + (cv.x - zv.x);
        o.y = zv.y + (cv.y - zv.y);
        o.z = zv.z + (cv.z - zv.z);
        o.w = zv.w + (cv.w - zv.w);
        ((float4*)out)[row * 64 + lane] = o;
        float dx = zv.x - cv.x, dy = zv.y - cv.y, dz = zv.z - cv.z, dw = zv.w - cv.w;
        ls += (double)dx * dx + (double)dy * dy + (double)dz * dz + (double)dw * dw;
    }
    #pragma unroll
    for (int off = 32; off > 0; off >>= 1) ls += __shfl_down(ls, off);
    if (lane == 0) sredD[wid] = ls;
    __syncthreads();
    if (tid == 0) lparts[tb] = (sredD[0] + sredD[1]) + (sredD[2] + sredD[3]);
}

// ---- exact np-f32-chain recheck: ONE WAVE PER (row, block) PAIR, no barriers. ----
__global__ __launch_bounds__(256)
void vq_recheck_pairs(const float* __restrict__ z, const float* __restrict__ cbT,
                      const float* __restrict__ cnorm, const int* __restrict__ flist,
                      const unsigned int* __restrict__ fcount,
                      unsigned long long* __restrict__ rck)
{
    const int tid  = threadIdx.x;
    const int wid  = tid >> 6;
    const int lane = tid & 63;
    const unsigned int cnt = *fcount;

    for (unsigned int p = blockIdx.x * 4 + wid; p < cnt; p += gridDim.x * 4) {
        const int e   = flist[p];
        const int row = e & 0x1FFFF;
        const int blk = ((unsigned int)e) >> 17;
        const float* zr = z + (size_t)row * DIM;

        float4 zv = ((const float4*)zr)[lane];
        double s = 0.0;
        s = fma((double)zv.x, (double)zv.x, s);
        s = fma((double)zv.y, (double)zv.y, s);
        s = fma((double)zv.z, (double)zv.z, s);
        s = fma((double)zv.w, (double)zv.w, s);
        #pragma unroll
        for (int off = 32; off > 0; off >>= 1) s += __shfl_xor(s, off);
        const float zz = (float)s;

        const int c0 = blk * 128 + lane;        // lane's two codes (c0 < c0+64)
        float e0 = 0.0f, e1 = 0.0f;
        #pragma unroll 8
        for (int d4 = 0; d4 < 64; ++d4) {       // strict sequential k = 0..255
            float4 zq = ((const float4*)zr)[d4];             // wave-uniform, L1-hot
            float4 a  = ((const float4*)cbT)[d4 * KC + c0];  // coalesced over lanes
            float4 b  = ((const float4*)cbT)[d4 * KC + c0 + 64];
            e0 = fmaf(zq.x, a.x, e0); e0 = fmaf(zq.y, a.y, e0);
            e0 = fmaf(zq.z, a.z, e0); e0 = fmaf(zq.w, a.w, e0);
            e1 = fmaf(zq.x, b.x, e1); e1 = fmaf(zq.y, b.y, e1);
            e1 = fmaf(zq.z, b.z, e1); e1 = fmaf(zq.w, b.w, e1);
        }
        const float dq0 = fmaf(e0, -2.0f, zz + cnorm[c0]);       // fl(fl(zz+cc) - fl(2e))
        const float dq1 = fmaf(e1, -2.0f, zz + cnorm[c0 + 64]);
        unsigned long long k0 = ((unsigned long long)__float_as_uint(dq0) << 32) | (unsigned int)c0;
        unsigned long long k1 = ((unsigned long long)__float_as_uint(dq1) << 32) | (unsigned int)(c0 + 64);
        unsigned long long k = k0 < k1 ? k0 : k1;
        #pragma unroll
        for (int off = 32; off > 0; off >>= 1) {
            unsigned long long o = __shfl_xor(k, off);
            k = o < k ? o : k;
        }
        if (lane == 0) atomicMin(&rck[row], k);
    }
}

// ---- fixup: one wave per pair (duplicates idempotent): final idx + z_st row rewrite
__global__ __launch_bounds__(256)
void vq_fixup(const float* __restrict__ z, const float* __restrict__ cb,
              const int* __restrict__ flist, const unsigned int* __restrict__ fcount,
              const unsigned long long* __restrict__ rck,
              float* __restrict__ out, float* __restrict__ out_idx)
{
    const int tid  = threadIdx.x;
    const int wid  = tid >> 6;
    const int lane = tid & 63;
    const unsigned int cnt = *fcount;

    for (unsigned int p = blockIdx.x * 4 + wid; p < cnt; p += gridDim.x * 4) {
        const int row  = flist[p] & 0x1FFFF;
        const int code = (int)(unsigned int)rck[row];   // low 32 bits = winning code
        float4 zv = ((const float4*)z)[(size_t)row * 64 + lane];
        float4 cv = ((const float4*)cb)[(size_t)code * 64 + lane];
        float4 o;
        o.x = zv.x + (cv.x - zv.x);
        o.y = zv.y + (cv.y - zv.y);
        o.z = zv.z + (cv.z - zv.z);
        o.w = zv.w + (cv.w - zv.w);
        ((float4*)out)[(size_t)row * 64 + lane] = o;
        if (lane == 0) out_idx[row] = (float)code;
    }
}

__global__ void vq_loss_final(const double* __restrict__ lparts, float* __restrict__ out_loss) {
    __shared__ double s[256];
    const int tid = threadIdx.x;
    double a = 0.0;
    for (int i = tid; i < NBLK; i += 256) a += lparts[i];
    s[tid] = a;
    __syncthreads();
    for (int sft = 128; sft > 0; sft >>= 1) {
        if (tid < sft) s[tid] += s[tid + sft];
        __syncthreads();
    }
    if (tid == 0) {
        float mean = (float)(s[0] / (double)((size_t)N_TOK * DIM));
        out_loss[0] = 0.25f * mean + mean;   // commit + codebook, reference op order
    }
}

extern "C" void kernel_launch(void* const* d_in, const int* in_sizes, int n_in,
                              void* d_out, int out_size, void* d_ws, size_t ws_size,
                              hipStream_t stream) {
    const float* z  = (const float*)d_in[0];
    const float* cb = (const float*)d_in[1];
    float* out = (float*)d_out;
    char* ws = (char*)d_ws;

    unsigned short*     cb16F  = (unsigned short*)(ws);
    float*              cnsF   = (float*)(ws + 524288);
    float*              cnorm  = (float*)(ws + 528384);
    float*              cbT    = (float*)(ws + 532480);
    unsigned int*       fcount = (unsigned int*)(ws + 1581056);
    int*                flist  = (int*)(ws + 1581120);
    unsigned long long* rck    = (unsigned long long*)(ws + 5775424);
    double*             lparts = (double*)(ws + 6824000);

    float* out_idx  = out + (size_t)N_TOK * DIM;
    float* out_loss = out_idx + N_TOK;

    vq_prep_cb<<<KC / 4, 256, 0, stream>>>(cb, cb16F, cnsF, cnorm, fcount);
    vq_transpose<<<(KC * DIM / 4) / 256, 256, 0, stream>>>(cb, cbT);
    vq_scores_fused<<<NBLK, 256, 0, stream>>>(z, cb16F, cnsF, cb, out, out_idx,
                                              flist, fcount, rck, lparts);
    vq_recheck_pairs<<<1024, 256, 0, stream>>>(z, cbT, cnorm, flist, fcount, rck);
    vq_fixup<<<512, 256, 0, stream>>>(z, cb, flist, fcount, rck, out, out_idx);
    vq_loss_final<<<1, 256, 0, stream>>>(lparts, out_loss);
}

// Round 13
// 422.720 us; speedup vs baseline: 1.2312x; 1.0227x over previous
//
#include <hip/hip_runtime.h>

#define N_TOK 131072
#define KC    1024
#define DIM   256
#define GAP_THR 5e-4f
#define NBLK  (N_TOK / 128)      // 1024 token blocks

typedef __attribute__((ext_vector_type(8)))  short bf16x8;
typedef __attribute__((ext_vector_type(16))) float f32x16;

__device__ __forceinline__ unsigned short f2bf(float f) {
    unsigned int u = __float_as_uint(f);
    unsigned int r = (u + 0x7fffu + ((u >> 16) & 1u)) >> 16;   // RNE
    return (unsigned short)r;
}

// ================= ws layout =================
// 0       : cb16F (bf16)     524288 B   fragment-ordered: [g(32)][step(16)][hi*32+l31][8]
// 524288  : cnsF  (f32)        4096 B   [g(32)][hi(2)][r(16)] = -cnorm/2
// 528384  : cnorm (f32)        4096 B
// 532480  : cbT   (f32)     1048576 B   cbT[d4][code][4] transposed codebook (recheck)
// 1581056 : fcount (u32)         64 B
// 1581120 : flist (int)     4194304 B   entry = row | (blk << 17), one per pair
// 5775424 : rck   (u64)     1048576 B   per-row (dq_bits<<32 | code) atomicMin
// 6824000 : lparts (f64)       8192 B
#define WS_NEED 6832192ull

// cb -> fragment-ordered bf16 + cnsF + cbT + f64 norms (one wave per code); zeroes fcount
__global__ void vq_prep_cb(const float* __restrict__ cb, unsigned short* __restrict__ cb16F,
                           float* __restrict__ cnsF, float* __restrict__ cnorm,
                           float* __restrict__ cbT, unsigned int* __restrict__ fcount) {
    if (blockIdx.x == 0 && threadIdx.x == 0) *fcount = 0u;
    int code = blockIdx.x * 4 + (threadIdx.x >> 6);
    int lane = threadIdx.x & 63;
    float4 v = ((const float4*)cb)[(size_t)code * 64 + lane];
    ((float4*)cbT)[(size_t)lane * KC + code] = v;        // fused transpose (d4 = lane)
    ushort4 h;
    h.x = f2bf(v.x); h.y = f2bf(v.y); h.z = f2bf(v.z); h.w = f2bf(v.w);
    // fragment destination for dims d = 4*lane .. +4 (stays within one 8-dim unit)
    int d = lane * 4;
    int kb = d >> 6, ks = (d >> 4) & 3, hi = (d >> 3) & 1;
    int step = kb * 4 + ks;
    int g = code >> 5, l31 = code & 31;
    size_t sidx = ((size_t)(g * 16 + step) * 64 + hi * 32 + l31) * 8 + (d & 7);
    *(ushort4*)(cb16F + sidx) = h;           // 8 B aligned
    double s = 0.0;
    s = fma((double)v.x, (double)v.x, s);
    s = fma((double)v.y, (double)v.y, s);
    s = fma((double)v.z, (double)v.z, s);
    s = fma((double)v.w, (double)v.w, s);
    #pragma unroll
    for (int off = 32; off > 0; off >>= 1) s += __shfl_xor(s, off);
    if (lane == 0) {
        float cn = (float)s;
        cnorm[code] = cn;
        int row = code & 31;                 // C-layout row within the 32-code tile
        int hic = (row >> 2) & 1;
        int rc  = (row & 3) | ((row >> 3) << 2);
        cnsF[(g * 2 + hic) * 16 + rc] = -0.5f * cn;   // exact: acc-init = -cc/2
    }
}

// ---- Fused scores: NO LDS / NO barriers in the main loop (R11 structure).
// Block: 4 waves; wave = 32 tokens x (64 codes per sub-block) x 16 sub-blocks.
// B (tokens) register-resident bf16 frags; A (codes) coalesced 1KB wave-loads from
// L2-resident fragment-ordered cb16F; cnorm enters via f32-exact acc init (-cc/2).
// launch_bounds(256,3): VGPR cap 170 -- R11's (256,4) cap=128 forced bfr spills.
__global__ __launch_bounds__(256, 3)
void vq_scores_fused(const float* __restrict__ z, const unsigned short* __restrict__ cb16F,
                     const float* __restrict__ cnsF, const float* __restrict__ cb,
                     float* __restrict__ out, float* __restrict__ out_idx,
                     int* __restrict__ flist, unsigned int* __restrict__ fcount,
                     unsigned long long* __restrict__ rck, double* __restrict__ lparts)
{
    __shared__ float  bm1L[16][128];    // 8 KB : per-sub-block per-token min
    __shared__ double sredD[4];

    const int tid  = threadIdx.x;
    const int lane = tid & 63;
    const int l31  = lane & 31;
    const int hi   = lane >> 5;
    const int wid  = tid >> 6;
    const int tb   = blockIdx.x;
    const int ltok = wid * 32 + l31;    // local token 0..127

    // ---- B fragments from global f32 (hi-pairs consume 64B line chunks) + f64 zz ----
    bf16x8 bfr[4][4];
    const float* zr = z + (size_t)(tb * 128 + ltok) * DIM;
    double s = 0.0;
    #pragma unroll
    for (int kb = 0; kb < 4; ++kb)
        #pragma unroll
        for (int ks = 0; ks < 4; ++ks) {
            const int d0 = kb * 64 + ks * 16 + hi * 8;
            float4 x = *(const float4*)(zr + d0);
            float4 y = *(const float4*)(zr + d0 + 4);
            s = fma((double)x.x, (double)x.x, s);
            s = fma((double)x.y, (double)x.y, s);
            s = fma((double)x.z, (double)x.z, s);
            s = fma((double)x.w, (double)x.w, s);
            s = fma((double)y.x, (double)y.x, s);
            s = fma((double)y.y, (double)y.y, s);
            s = fma((double)y.z, (double)y.z, s);
            s = fma((double)y.w, (double)y.w, s);
            bf16x8 v;
            v[0] = (short)f2bf(x.x); v[1] = (short)f2bf(x.y);
            v[2] = (short)f2bf(x.z); v[3] = (short)f2bf(x.w);
            v[4] = (short)f2bf(y.x); v[5] = (short)f2bf(y.y);
            v[6] = (short)f2bf(y.z); v[7] = (short)f2bf(y.w);
            bfr[kb][ks] = v;
        }
    s += __shfl_xor(s, 32);             // partner lane holds the other dim-half
    const float zzr = (float)s;         // uniform per-row shift: argmin-invariant

    float gm1 = 3.0e38f, gm2 = 3.0e38f; int gid_ = 0x7fffffff;
    const bf16x8* AF = (const bf16x8*)cb16F;     // 16B fragment units

    #pragma unroll 1
    for (int sb = 0; sb < 16; ++sb) {
        // acc init = -cc/2 (f32 exact), broadcast loads from cnsF
        f32x16 acc[2];
        #pragma unroll
        for (int gi = 0; gi < 2; ++gi) {
            const float4* cp = (const float4*)(cnsF + (((sb * 2 + gi) * 2 + hi) << 4));
            float4 c0 = cp[0], c1 = cp[1], c2 = cp[2], c3 = cp[3];
            acc[gi][0]  = c0.x; acc[gi][1]  = c0.y; acc[gi][2]  = c0.z; acc[gi][3]  = c0.w;
            acc[gi][4]  = c1.x; acc[gi][5]  = c1.y; acc[gi][6]  = c1.z; acc[gi][7]  = c1.w;
            acc[gi][8]  = c2.x; acc[gi][9]  = c2.y; acc[gi][10] = c2.z; acc[gi][11] = c2.w;
            acc[gi][12] = c3.x; acc[gi][13] = c3.y; acc[gi][14] = c3.z; acc[gi][15] = c3.w;
        }

        #pragma unroll
        for (int kb = 0; kb < 4; ++kb)
            #pragma unroll
            for (int ks = 0; ks < 4; ++ks) {
                const bf16x8 bv = bfr[kb][ks];
                #pragma unroll
                for (int gi = 0; gi < 2; ++gi) {     // two independent MFMA chains
                    bf16x8 af = AF[(size_t)((sb * 2 + gi) * 16 + kb * 4 + ks) * 64 + lane];
                    acc[gi] = __builtin_amdgcn_mfma_f32_32x32x16_bf16(af, bv, acc[gi], 0, 0, 0);
                }
            }

        // epilogue (register-only): dq = fmaf(acc, -2, zz); top-2 + lowest-index.
        // C layout (32x32): col=lane&31 (token), row=(r&3)+8*(r>>2)+4*hi (code)
        float c1v = 3.0e38f, c2v = 3.0e38f;
        #pragma unroll
        for (int gi = 0; gi < 2; ++gi)
            #pragma unroll
            for (int r = 0; r < 16; ++r) {
                float dq = fmaf(acc[gi][r], -2.0f, zzr);
                acc[gi][r] = dq;
                float hv = fmaxf(c1v, dq);
                c1v = fminf(c1v, dq);
                c2v = fminf(c2v, hv);              // dup minima -> gap 0 -> flagged
            }
        int ci = 0x7fffffff;
        #pragma unroll
        for (int gi = 0; gi < 2; ++gi)
            #pragma unroll
            for (int r = 0; r < 16; ++r) {
                int code = (sb * 2 + gi) * 32 + (r & 3) + 8 * (r >> 2) + 4 * hi;
                ci = min(ci, (acc[gi][r] == c1v) ? code : 0x7fffffff);
            }
        // merge lane <-> lane^32 (same token, other code rows)
        float o1 = __shfl_xor(c1v, 32);
        float o2 = __shfl_xor(c2v, 32);
        int  oi  = __shfl_xor(ci, 32);
        float nm2 = fminf(fminf(c2v, o2), fmaxf(c1v, o1));
        int  ni  = (o1 < c1v || (o1 == c1v && oi < ci)) ? oi : ci;
        float nm1 = fminf(c1v, o1);
        if (hi == 0) bm1L[sb][ltok] = nm1;
        float ng2 = fminf(fminf(gm2, nm2), fmaxf(gm1, nm1));
        if (nm1 < gm1 || (nm1 == gm1 && ni < gid_)) { gm1 = nm1; gid_ = ni; }
        gm2 = ng2;
    }

    // ---- flag pairs + provisional index (hi==0 lane reads back its own bm1L writes) ----
    const int rowg = tb * 128 + ltok;
    if (hi == 0) {
        out_idx[rowg] = (float)gid_;
        float gap = gm2 - gm1;
        if (!(gap > GAP_THR)) {           // near-tie or NaN safety -> exact recheck
            rck[rowg] = ~0ull;
            #pragma unroll
            for (int c = 0; c < 8; ++c) {
                float bmin = fminf(bm1L[2 * c][ltok], bm1L[2 * c + 1][ltok]);
                if (bmin <= gm1 + GAP_THR) {
                    unsigned int p = atomicAdd(fcount, 1u);
                    flist[p] = rowg | (c << 17);
                }
            }
        }
    }

    // ---- fused z_st + loss: wave writes its own 32 rows (z re-read L2/L3-hot) ----
    double ls = 0.0;
    #pragma unroll 4
    for (int r = 0; r < 32; ++r) {
        int idx = __shfl(gid_, r);                       // wave-uniform per row
        size_t row = (size_t)tb * 128 + wid * 32 + r;
        float4 zv = ((const float4*)z)[row * 64 + lane];
        float4 cv = ((const float4*)cb)[(size_t)idx * 64 + lane];
        float4 o;
        o.x = zv.x + (cv.x - zv.x);
        o.y = zv.y + (cv.y - zv.y);
        o.z = zv.z + (cv.z - zv.z);
        o.w = zv.w + (cv.w - zv.w);
        ((float4*)out)[row * 64 + lane] = o;
        float dx = zv.x - cv.x, dy = zv.y - cv.y, dz = zv.z - cv.z, dw = zv.w - cv.w;
        ls += (double)dx * dx + (double)dy * dy + (double)dz * dz + (double)dw * dw;
    }
    #pragma unroll
    for (int off = 32; off > 0; off >>= 1) ls += __shfl_down(ls, off);
    if (lane == 0) sredD[wid] = ls;
    __syncthreads();
    if (tid == 0) lparts[tb] = (sredD[0] + sredD[1]) + (sredD[2] + sredD[3]);
}

// ---- exact np-f32-chain recheck: ONE WAVE PER (row, block) PAIR, no barriers. ----
__global__ __launch_bounds__(256)
void vq_recheck_pairs(const float* __restrict__ z, const float* __restrict__ cbT,
                      const float* __restrict__ cnorm, const int* __restrict__ flist,
                      const unsigned int* __restrict__ fcount,
                      unsigned long long* __restrict__ rck)
{
    const int tid  = threadIdx.x;
    const int wid  = tid >> 6;
    const int lane = tid & 63;
    const unsigned int cnt = *fcount;

    for (unsigned int p = blockIdx.x * 4 + wid; p < cnt; p += gridDim.x * 4) {
        const int e   = flist[p];
        const int row = e & 0x1FFFF;
        const int blk = ((unsigned int)e) >> 17;
        const float* zr = z + (size_t)row * DIM;

        float4 zv = ((const float4*)zr)[lane];
        double s = 0.0;
        s = fma((double)zv.x, (double)zv.x, s);
        s = fma((double)zv.y, (double)zv.y, s);
        s = fma((double)zv.z, (double)zv.z, s);
        s = fma((double)zv.w, (double)zv.w, s);
        #pragma unroll
        for (int off = 32; off > 0; off >>= 1) s += __shfl_xor(s, off);
        const float zz = (float)s;

        const int c0 = blk * 128 + lane;        // lane's two codes (c0 < c0+64)
        float e0 = 0.0f, e1 = 0.0f;
        #pragma unroll 8
        for (int d4 = 0; d4 < 64; ++d4) {       // strict sequential k = 0..255
            float4 zq = ((const float4*)zr)[d4];             // wave-uniform, L1-hot
            float4 a  = ((const float4*)cbT)[d4 * KC + c0];  // coalesced over lanes
            float4 b  = ((const float4*)cbT)[d4 * KC + c0 + 64];
            e0 = fmaf(zq.x, a.x, e0); e0 = fmaf(zq.y, a.y, e0);
            e0 = fmaf(zq.z, a.z, e0); e0 = fmaf(zq.w, a.w, e0);
            e1 = fmaf(zq.x, b.x, e1); e1 = fmaf(zq.y, b.y, e1);
            e1 = fmaf(zq.z, b.z, e1); e1 = fmaf(zq.w, b.w, e1);
        }
        const float dq0 = fmaf(e0, -2.0f, zz + cnorm[c0]);       // fl(fl(zz+cc) - fl(2e))
        const float dq1 = fmaf(e1, -2.0f, zz + cnorm[c0 + 64]);
        unsigned long long k0 = ((unsigned long long)__float_as_uint(dq0) << 32) | (unsigned int)c0;
        unsigned long long k1 = ((unsigned long long)__float_as_uint(dq1) << 32) | (unsigned int)(c0 + 64);
        unsigned long long k = k0 < k1 ? k0 : k1;
        #pragma unroll
        for (int off = 32; off > 0; off >>= 1) {
            unsigned long long o = __shfl_xor(k, off);
            k = o < k ? o : k;
        }
        if (lane == 0) atomicMin(&rck[row], k);
    }
}

// ---- fixup: one wave per pair (duplicates idempotent): final idx + z_st row rewrite
__global__ __launch_bounds__(256)
void vq_fixup(const float* __restrict__ z, const float* __restrict__ cb,
              const int* __restrict__ flist, const unsigned int* __restrict__ fcount,
              const unsigned long long* __restrict__ rck,
              float* __restrict__ out, float* __restrict__ out_idx)
{
    const int tid  = threadIdx.x;
    const int wid  = tid >> 6;
    const int lane = tid & 63;
    const unsigned int cnt = *fcount;

    for (unsigned int p = blockIdx.x * 4 + wid; p < cnt; p += gridDim.x * 4) {
        const int row  = flist[p] & 0x1FFFF;
        const int code = (int)(unsigned int)rck[row];   // low 32 bits = winning code
        float4 zv = ((const float4*)z)[(size_t)row * 64 + lane];
        float4 cv = ((const float4*)cb)[(size_t)code * 64 + lane];
        float4 o;
        o.x = zv.x + (cv.x - zv.x);
        o.y = zv.y + (cv.y - zv.y);
        o.z = zv.z + (cv.z - zv.z);
        o.w = zv.w + (cv.w - zv.w);
        ((float4*)out)[(size_t)row * 64 + lane] = o;
        if (lane == 0) out_idx[row] = (float)code;
    }
}

__global__ void vq_loss_final(const double* __restrict__ lparts, float* __restrict__ out_loss) {
    __shared__ double s[256];
    const int tid = threadIdx.x;
    double a = 0.0;
    for (int i = tid; i < NBLK; i += 256) a += lparts[i];
    s[tid] = a;
    __syncthreads();
    for (int sft = 128; sft > 0; sft >>= 1) {
        if (tid < sft) s[tid] += s[tid + sft];
        __syncthreads();
    }
    if (tid == 0) {
        float mean = (float)(s[0] / (double)((size_t)N_TOK * DIM));
        out_loss[0] = 0.25f * mean + mean;   // commit + codebook, reference op order
    }
}

extern "C" void kernel_launch(void* const* d_in, const int* in_sizes, int n_in,
                              void* d_out, int out_size, void* d_ws, size_t ws_size,
                              hipStream_t stream) {
    const float* z  = (const float*)d_in[0];
    const float* cb = (const float*)d_in[1];
    float* out = (float*)d_out;
    char* ws = (char*)d_ws;

    unsigned short*     cb16F  = (unsigned short*)(ws);
    float*              cnsF   = (float*)(ws + 524288);
    float*              cnorm  = (float*)(ws + 528384);
    float*              cbT    = (float*)(ws + 532480);
    unsigned int*       fcount = (unsigned int*)(ws + 1581056);
    int*                flist  = (int*)(ws + 1581120);
    unsigned long long* rck    = (unsigned long long*)(ws + 5775424);
    double*             lparts = (double*)(ws + 6824000);

    float* out_idx  = out + (size_t)N_TOK * DIM;
    float* out_loss = out_idx + N_TOK;

    vq_prep_cb<<<KC / 4, 256, 0, stream>>>(cb, cb16F, cnsF, cnorm, cbT, fcount);
    vq_scores_fused<<<NBLK, 256, 0, stream>>>(z, cb16F, cnsF, cb, out, out_idx,
                                              flist, fcount, rck, lparts);
    vq_recheck_pairs<<<1024, 256, 0, stream>>>(z, cbT, cnorm, flist, fcount, rck);
    vq_fixup<<<512, 256, 0, stream>>>(z, cb, flist, fcount, rck, out, out_idx);
    vq_loss_final<<<1, 256, 0, stream>>>(lparts, out_loss);
}